// Round 9
// baseline (72.424 us; speedup 1.0000x reference)
//
#include <hip/hip_runtime.h>
#include <hip/hip_bf16.h>
#include <math.h>

// Problem constants
#define Bb 4
#define Nn 512
#define Mm 64
#define Ff 256
#define Qq 16
#define Hh 8
#define Rr 32
#define FFNH 512
#define ROWS (Bb*Nn)          // 2048
#define KIN (Ff+Qq)           // 272
#define KINP 288              // padded to 9*32
#define KOUT (2*Ff+Rr)        // 544 = 17*32

typedef short short8 __attribute__((ext_vector_type(8)));
typedef unsigned short ushort8 __attribute__((ext_vector_type(8)));
typedef float f32x4 __attribute__((ext_vector_type(4)));

__device__ inline unsigned short f2b(float f) {
    union { float f; unsigned u; } c; c.f = f;
    unsigned r = c.u + 0x7fffu + ((c.u >> 16) & 1u);
    return (unsigned short)(r >> 16);
}
__device__ inline float b2f(unsigned short u) {
    union { unsigned u; float f; } c; c.u = ((unsigned)u) << 16;
    return c.f;
}

// arena segments (ushort offsets)
#define OFF_CENTER 0
#define OFF_WQKV   (OFF_CENTER + ROWS*KINP)            // 589824
#define OFF_WOUT   (OFF_WQKV + 768*KINP)               // 811008
#define OFF_WF1    (OFF_WOUT + Ff*KOUT)                // 950272
#define OFF_WF2    (OFF_WF1 + FFNH*Ff)                 // 1081344
#define OFF_U      (OFF_WF2 + Ff*FFNH)                 // 1212416
#define OFF_QKVB   (OFF_U + ROWS*KOUT)                 // 2326528
#define CONV_TOTAL OFF_U                               // 1212416
#define CONV_BLK   (CONV_TOTAL/256)                    // 4736
#define A2U_BLK    (ROWS*Ff/256)                       // 2048
#define MSK_BLK    (Bb*Nn*Mm/256)                      // 512

// ---------------------------------------------------------------- prep: convert + U[:, :256]=bf16(a) + detect mask
__global__ __launch_bounds__(256) void prep(const float* __restrict__ a,
                                            const float* __restrict__ ch,
                                            const float* __restrict__ Wq,
                                            const float* __restrict__ Wk,
                                            const float* __restrict__ Wv,
                                            const float* __restrict__ Wout,
                                            const float* __restrict__ Wf1,
                                            const float* __restrict__ Wf2,
                                            const unsigned char* __restrict__ mask,
                                            int* __restrict__ flag,
                                            unsigned short* __restrict__ arena) {
    int bid = blockIdx.x, tid = threadIdx.x;
    if (bid < CONV_BLK) {
        int i = bid * 256 + tid;
        float v;
        if (i < OFF_WQKV) {
            int row = i / KINP, c = i - row * KINP;
            v = (c < Ff) ? a[(size_t)row * Ff + c] : (c < KIN ? ch[(size_t)row * Qq + (c - Ff)] : 0.f);
        } else if (i < OFF_WOUT) {
            int j = i - OFF_WQKV;
            int n = j / KINP, c = j - n * KINP;
            const float* W = n < 256 ? Wq : (n < 512 ? Wk : Wv);
            int nr = n & 255;
            v = (c < KIN) ? W[(size_t)nr * KIN + c] : 0.f;
        } else if (i < OFF_WF1) {
            v = Wout[i - OFF_WOUT];
        } else if (i < OFF_WF2) {
            v = Wf1[i - OFF_WF1];
        } else {
            v = Wf2[i - OFF_WF2];
        }
        arena[i] = f2b(v);
    } else if (bid < CONV_BLK + A2U_BLK) {
        int j = (bid - CONV_BLK) * 256 + tid;
        int row = j >> 8, col = j & 255;
        arena[OFF_U + (size_t)row * KOUT + col] = f2b(a[j]);
    } else {
        int i = (bid - CONV_BLK - A2U_BLK) * 256 + tid;
        if ((i & 3) && mask[i]) *flag = 1;
    }
}

// ---------------------------------------------------------------- QKV GEMM, direct-from-L2 frags, barrier-free
// grid 128 (16-row panels), 512 threads; wave w covers 96 cols (6 n-tiles)
__global__ __launch_bounds__(512) void qkv_gemm(const unsigned short* __restrict__ Ab,
                                                const unsigned short* __restrict__ Wb,
                                                const float* __restrict__ bq,
                                                const float* __restrict__ bk,
                                                const float* __restrict__ bv,
                                                unsigned short* __restrict__ QKVb) {
    int tid = threadIdx.x;
    int wave = tid >> 6, lane = tid & 63;
    int rowbase = blockIdx.x * 16;
    int cb = wave * 96;
    int lrow = lane & 15, ks = lane >> 4;

    const unsigned short* Ap = Ab + (size_t)(rowbase + lrow) * KINP + ks * 8;
    const unsigned short* Bp[6];
    #pragma unroll
    for (int nt = 0; nt < 6; ++nt)
        Bp[nt] = Wb + (size_t)(cb + nt * 16 + lrow) * KINP + ks * 8;

    f32x4 acc[6] = {};
    short8 aC = *reinterpret_cast<const short8*>(Ap);
    short8 bC[6];
    #pragma unroll
    for (int nt = 0; nt < 6; ++nt) bC[nt] = *reinterpret_cast<const short8*>(Bp[nt]);
    for (int t = 0; t < 8; ++t) {
        short8 aN = *reinterpret_cast<const short8*>(Ap + (t + 1) * 32);
        short8 bN[6];
        #pragma unroll
        for (int nt = 0; nt < 6; ++nt) bN[nt] = *reinterpret_cast<const short8*>(Bp[nt] + (t + 1) * 32);
        #pragma unroll
        for (int nt = 0; nt < 6; ++nt)
            acc[nt] = __builtin_amdgcn_mfma_f32_16x16x32_bf16(aC, bC[nt], acc[nt], 0, 0, 0);
        aC = aN;
        #pragma unroll
        for (int nt = 0; nt < 6; ++nt) bC[nt] = bN[nt];
    }
    #pragma unroll
    for (int nt = 0; nt < 6; ++nt)
        acc[nt] = __builtin_amdgcn_mfma_f32_16x16x32_bf16(aC, bC[nt], acc[nt], 0, 0, 0);

    #pragma unroll
    for (int nt = 0; nt < 6; ++nt) {
        int col0 = cb + nt * 16;
        int sel = col0 >> 8;
        const float* bias = sel == 0 ? bq : (sel == 1 ? bk : bv);
        int col = col0 + (lane & 15);
        float badd = bias[(col0 & 255) + (lane & 15)];
        #pragma unroll
        for (int i = 0; i < 4; ++i) {
            int row = rowbase + (lane >> 4) * 4 + i;
            QKVb[(size_t)row * 768 + col] = f2b(acc[nt][i] + badd);
        }
    }
}

// ---------------------------------------------------------------- attention v3: bf16 K/V, double-buffered LDS tiles
__global__ __launch_bounds__(256) void attn_kernel(const unsigned short* __restrict__ QKV,
                                                   const int* __restrict__ idx_j,
                                                   const float* __restrict__ d_ij,
                                                   const void* __restrict__ mask,
                                                   const float* __restrict__ shifts,
                                                   const float* __restrict__ Wrb,
                                                   const float* __restrict__ brb,
                                                   const int* __restrict__ flag,
                                                   unsigned short* __restrict__ Ub) {
    __shared__ unsigned short Kt[2][16][280];
    __shared__ float rad[Mm][36];
    __shared__ float att[Hh][Mm];
    __shared__ float attbar[Mm];
    __shared__ int   jl[Mm];
    __shared__ float dv[Mm];
    __shared__ int   maskf[Mm];
    __shared__ float shs[Rr];

    int row = blockIdx.x;
    int b = row >> 9;
    int tid = threadIdx.x;
    bool boolmask = (*flag != 0);

    if (tid < Mm) jl[tid] = idx_j[row * Mm + tid];
    else if (tid < 128) { int m = tid - 64; dv[m] = d_ij[row * Mm + m]; }
    else if (tid < 160) shs[tid - 128] = shifts[tid - 128];
    else if (tid >= 192) {
        int m = tid - 192;
        maskf[m] = boolmask ? (int)((const unsigned char*)mask)[row * Mm + m]
                            : ((const int*)mask)[row * Mm + m];
    }

    int half = tid & 1;
    int p = tid >> 1;
    int hh = p >> 4;
    int ml = p & 15;
    float qf[16];
    {
        const unsigned short* qrow = QKV + (size_t)row * 768 + hh * 32 + half * 16;
        ushort8 q0 = *reinterpret_cast<const ushort8*>(qrow);
        ushort8 q1 = *reinterpret_cast<const ushort8*>(qrow + 8);
        #pragma unroll
        for (int i = 0; i < 8; ++i) { qf[i] = b2f(q0[i]); qf[8 + i] = b2f(q1[i]); }
    }
    float4 wreg[4];
    #pragma unroll
    for (int c = 0; c < 4; ++c)
        wreg[c] = *reinterpret_cast<const float4*>(Wrb + hh * Rr + half * 16 + c * 4);
    float brbh = brb[hh];
    __syncthreads();

    auto stage = [&](int t, int seg, int buf) {
        #pragma unroll
        for (int q = 0; q < 2; ++q) {
            int chunk = q * 256 + tid;
            int r = chunk >> 5, s = chunk & 31;
            int j = jl[t * 16 + r];
            const uint4* src = reinterpret_cast<const uint4*>(QKV + (size_t)(b * Nn + j) * 768 + seg);
            uint4 v = src[s];
            *reinterpret_cast<uint4*>(&Kt[buf][r][s * 8]) = v;
        }
    };

    #pragma unroll
    for (int it = 0; it < 8; ++it) {
        int i = tid + it * 256;
        int m = i >> 5, r = i & 31;
        float t = dv[m] - shs[r];
        rad[m][r] = expf(-4.0f * t * t);
    }
    stage(0, 256, 0);
    __syncthreads();

    for (int t = 0; t < 4; ++t) {
        if (t < 3) stage(t + 1, 256, (t + 1) & 1);
        int buf = t & 1;
        const unsigned short* kr = &Kt[buf][ml][hh * 32 + half * 16];
        ushort8 k0 = *reinterpret_cast<const ushort8*>(kr);
        ushort8 k1 = *reinterpret_cast<const ushort8*>(kr + 8);
        float accK = 0.f;
        #pragma unroll
        for (int i = 0; i < 8; ++i) accK = fmaf(qf[i], b2f(k0[i]), accK);
        #pragma unroll
        for (int i = 0; i < 8; ++i) accK = fmaf(qf[8 + i], b2f(k1[i]), accK);
        float accR = 0.f;
        #pragma unroll
        for (int c = 0; c < 4; ++c) {
            float4 rv = *reinterpret_cast<const float4*>(&rad[t * 16 + ml][half * 16 + c * 4]);
            accR += wreg[c].x * rv.x + wreg[c].y * rv.y + wreg[c].z * rv.z + wreg[c].w * rv.w;
        }
        float tv = accK * 0.17677669529663687f + accR;
        tv += __shfl_xor(tv, 1);
        if (!half) {
            int m = t * 16 + ml;
            att[hh][m] = maskf[m] ? -INFINITY : (tv + brbh);
        }
        __syncthreads();
    }

    {
        int h = tid >> 5, l = tid & 31;
        float s0 = att[h][l], s1 = att[h][l + 32];
        float mx = fmaxf(s0, s1);
        #pragma unroll
        for (int off = 16; off; off >>= 1) mx = fmaxf(mx, __shfl_xor(mx, off, 32));
        float e0 = 0.f, e1 = 0.f;
        if (mx != -INFINITY) {
            e0 = expf(s0 - mx);
            e1 = expf(s1 - mx);
        }
        float sm = e0 + e1;
        #pragma unroll
        for (int off = 16; off; off >>= 1) sm += __shfl_xor(sm, off, 32);
        float inv = sm > 0.f ? 1.f / sm : 0.f;
        att[h][l] = e0 * inv;
        att[h][l + 32] = e1 * inv;
    }
    stage(0, 512, 0);
    __syncthreads();

    float ctx = 0.f;
    int h2 = tid >> 5, d0 = tid & 31;
    for (int t = 0; t < 4; ++t) {
        if (t < 3) stage(t + 1, 512, (t + 1) & 1);
        int buf = t & 1;
        #pragma unroll
        for (int m = 0; m < 16; ++m)
            ctx = fmaf(att[h2][t * 16 + m], b2f(Kt[buf][m][h2 * 32 + d0]), ctx);
        if (t == 0 && tid < Mm) {
            float sv = 0.f;
            #pragma unroll
            for (int h = 0; h < Hh; ++h) sv += att[h][tid];
            attbar[tid] = sv * 0.125f;
        }
        __syncthreads();
    }

    Ub[(size_t)row * KOUT + Ff + tid] = f2b(ctx);

    if (tid < 64) {
        int g = tid >> 1;
        float acc = 0.f;
        #pragma unroll
        for (int i = 0; i < 32; ++i) {
            int m = half * 32 + i;
            acc = fmaf(attbar[m], rad[m][g], acc);
        }
        acc += __shfl_xor(acc, 1);
        if (!half) Ub[(size_t)row * KOUT + 2 * Ff + g] = f2b(acc);
    }
}

// ---------------------------------------------------------------- tail: Wout -> LN1 -> FFN1(GELU) -> FFN2 -> LN2
// grid 128 (16-row panels), 512 threads (8 waves). Direct-from-L2 MFMA frags, no K-loop barriers.
__global__ __launch_bounds__(512) void tail_kernel(const unsigned short* __restrict__ Ub,
                                                   const unsigned short* __restrict__ Woutb,
                                                   const unsigned short* __restrict__ Wf1b,
                                                   const unsigned short* __restrict__ Wf2b,
                                                   const float* __restrict__ a,
                                                   const float* __restrict__ bout,
                                                   const float* __restrict__ g1, const float* __restrict__ b1,
                                                   const float* __restrict__ bf1,
                                                   const float* __restrict__ bf2,
                                                   const float* __restrict__ g2, const float* __restrict__ b2,
                                                   float* __restrict__ outp) {
    __shared__ float xs[16][264];           // residual carrier: pre-LN1 sum, then LN1 output x
    __shared__ unsigned short xh[16][264];  // LN1 output bf16
    __shared__ unsigned short hb[16][520];  // GELU(h) bf16

    int tid = threadIdx.x;
    int wave = tid >> 6, lane = tid & 63;
    int rowbase = blockIdx.x * 16;
    int lrow = lane & 15, ks = lane >> 4;

    // prefill xs = a + bout
    {
        int r = tid >> 5, c = (tid & 31) * 8;
        float4 a0 = *reinterpret_cast<const float4*>(a + (size_t)(rowbase + r) * Ff + c);
        float4 a1 = *reinterpret_cast<const float4*>(a + (size_t)(rowbase + r) * Ff + c + 4);
        float4 o0 = *reinterpret_cast<const float4*>(bout + c);
        float4 o1 = *reinterpret_cast<const float4*>(bout + c + 4);
        xs[r][c + 0] = a0.x + o0.x; xs[r][c + 1] = a0.y + o0.y;
        xs[r][c + 2] = a0.z + o0.z; xs[r][c + 3] = a0.w + o0.w;
        xs[r][c + 4] = a1.x + o1.x; xs[r][c + 5] = a1.y + o1.y;
        xs[r][c + 6] = a1.z + o1.z; xs[r][c + 7] = a1.w + o1.w;
    }
    __syncthreads();

    // ---- Wout: 16x256, K=544 (17 tiles). wave covers 32 cols (2 n-tiles)
    {
        int cb = wave * 32;
        const unsigned short* Ap = Ub + (size_t)(rowbase + lrow) * KOUT + ks * 8;
        const unsigned short* B0 = Woutb + (size_t)(cb + lrow) * KOUT + ks * 8;
        const unsigned short* B1 = Woutb + (size_t)(cb + 16 + lrow) * KOUT + ks * 8;
        f32x4 acc0 = {}, acc1 = {};
        short8 aC = *reinterpret_cast<const short8*>(Ap);
        short8 b0C = *reinterpret_cast<const short8*>(B0);
        short8 b1C = *reinterpret_cast<const short8*>(B1);
        for (int t = 0; t < 16; ++t) {
            short8 aN = *reinterpret_cast<const short8*>(Ap + (t + 1) * 32);
            short8 b0N = *reinterpret_cast<const short8*>(B0 + (t + 1) * 32);
            short8 b1N = *reinterpret_cast<const short8*>(B1 + (t + 1) * 32);
            acc0 = __builtin_amdgcn_mfma_f32_16x16x32_bf16(aC, b0C, acc0, 0, 0, 0);
            acc1 = __builtin_amdgcn_mfma_f32_16x16x32_bf16(aC, b1C, acc1, 0, 0, 0);
            aC = aN; b0C = b0N; b1C = b1N;
        }
        acc0 = __builtin_amdgcn_mfma_f32_16x16x32_bf16(aC, b0C, acc0, 0, 0, 0);
        acc1 = __builtin_amdgcn_mfma_f32_16x16x32_bf16(aC, b1C, acc1, 0, 0, 0);
        // scatter-add into xs
        #pragma unroll
        for (int i = 0; i < 4; ++i) {
            int r = (lane >> 4) * 4 + i;
            xs[r][cb + (lane & 15)] += acc0[i];
            xs[r][cb + 16 + (lane & 15)] += acc1[i];
        }
    }
    __syncthreads();

    // ---- LN1: wave handles 2 rows; writes x (fp32) back to xs AND bf16 to xh
    {
        int r = wave * 2 + (lane >> 5);
        int c0 = lane & 31;
        float v[8]; float sm = 0.f;
        #pragma unroll
        for (int j = 0; j < 8; ++j) { v[j] = xs[r][c0 + 32 * j]; sm += v[j]; }
        #pragma unroll
        for (int o = 16; o; o >>= 1) sm += __shfl_xor(sm, o);
        float mu = sm * (1.f / Ff);
        float s2 = 0.f;
        #pragma unroll
        for (int j = 0; j < 8; ++j) { float d = v[j] - mu; s2 += d * d; }
        #pragma unroll
        for (int o = 16; o; o >>= 1) s2 += __shfl_xor(s2, o);
        float inv = rsqrtf(s2 * (1.f / Ff) + 1e-5f);
        #pragma unroll
        for (int j = 0; j < 8; ++j) {
            int c = c0 + 32 * j;
            float res = (v[j] - mu) * inv * g1[c] + b1[c];
            xs[r][c] = res;                 // residual carrier = LN1 OUTPUT (bug fix)
            xh[r][c] = f2b(res);
        }
    }
    __syncthreads();

    // ---- FFN1: 16x512, K=256 (8 tiles). wave covers 64 cols (4 n-tiles). A from LDS xh.
    {
        int cb = wave * 64;
        const unsigned short* Bp[4];
        #pragma unroll
        for (int nt = 0; nt < 4; ++nt)
            Bp[nt] = Wf1b + (size_t)(cb + nt * 16 + lrow) * Ff + ks * 8;
        f32x4 acc[4] = {};
        short8 bC[4];
        #pragma unroll
        for (int nt = 0; nt < 4; ++nt) bC[nt] = *reinterpret_cast<const short8*>(Bp[nt]);
        for (int t = 0; t < 8; ++t) {
            short8 bN[4];
            if (t < 7) {
                #pragma unroll
                for (int nt = 0; nt < 4; ++nt) bN[nt] = *reinterpret_cast<const short8*>(Bp[nt] + (t + 1) * 32);
            }
            short8 aC = *reinterpret_cast<const short8*>(&xh[lrow][t * 32 + ks * 8]);
            #pragma unroll
            for (int nt = 0; nt < 4; ++nt)
                acc[nt] = __builtin_amdgcn_mfma_f32_16x16x32_bf16(aC, bC[nt], acc[nt], 0, 0, 0);
            if (t < 7) {
                #pragma unroll
                for (int nt = 0; nt < 4; ++nt) bC[nt] = bN[nt];
            }
        }
        #pragma unroll
        for (int nt = 0; nt < 4; ++nt) {
            int col = cb + nt * 16 + (lane & 15);
            float badd = bf1[col];
            #pragma unroll
            for (int i = 0; i < 4; ++i) {
                int r = (lane >> 4) * 4 + i;
                float v = acc[nt][i] + badd;
                v = 0.5f * v * (1.0f + erff(v * 0.70710678118654752f));
                hb[r][col] = f2b(v);
            }
        }
    }
    __syncthreads();

    // ---- FFN2: 16x256, K=512 (16 tiles). wave covers 32 cols (2 n-tiles). A from LDS hb.
    {
        int cb = wave * 32;
        const unsigned short* B0 = Wf2b + (size_t)(cb + lrow) * FFNH + ks * 8;
        const unsigned short* B1 = Wf2b + (size_t)(cb + 16 + lrow) * FFNH + ks * 8;
        f32x4 acc0 = {}, acc1 = {};
        short8 b0C = *reinterpret_cast<const short8*>(B0);
        short8 b1C = *reinterpret_cast<const short8*>(B1);
        for (int t = 0; t < 15; ++t) {
            short8 b0N = *reinterpret_cast<const short8*>(B0 + (t + 1) * 32);
            short8 b1N = *reinterpret_cast<const short8*>(B1 + (t + 1) * 32);
            short8 aC = *reinterpret_cast<const short8*>(&hb[lrow][t * 32 + ks * 8]);
            acc0 = __builtin_amdgcn_mfma_f32_16x16x32_bf16(aC, b0C, acc0, 0, 0, 0);
            acc1 = __builtin_amdgcn_mfma_f32_16x16x32_bf16(aC, b1C, acc1, 0, 0, 0);
            b0C = b0N; b1C = b1N;
        }
        {
            short8 aC = *reinterpret_cast<const short8*>(&hb[lrow][15 * 32 + ks * 8]);
            acc0 = __builtin_amdgcn_mfma_f32_16x16x32_bf16(aC, b0C, acc0, 0, 0, 0);
            acc1 = __builtin_amdgcn_mfma_f32_16x16x32_bf16(aC, b1C, acc1, 0, 0, 0);
        }
        #pragma unroll
        for (int i = 0; i < 4; ++i) {
            int r = (lane >> 4) * 4 + i;
            int c0 = cb + (lane & 15), c1 = cb + 16 + (lane & 15);
            xs[r][c0] += acc0[i] + bf2[c0];
            xs[r][c1] += acc1[i] + bf2[c1];
        }
    }
    __syncthreads();

    // ---- LN2 -> global out
    {
        int r = wave * 2 + (lane >> 5);
        int c0 = lane & 31;
        float v[8]; float sm = 0.f;
        #pragma unroll
        for (int j = 0; j < 8; ++j) { v[j] = xs[r][c0 + 32 * j]; sm += v[j]; }
        #pragma unroll
        for (int o = 16; o; o >>= 1) sm += __shfl_xor(sm, o);
        float mu = sm * (1.f / Ff);
        float s2 = 0.f;
        #pragma unroll
        for (int j = 0; j < 8; ++j) { float d = v[j] - mu; s2 += d * d; }
        #pragma unroll
        for (int o = 16; o; o >>= 1) s2 += __shfl_xor(s2, o);
        float inv = rsqrtf(s2 * (1.f / Ff) + 1e-5f);
        #pragma unroll
        for (int j = 0; j < 8; ++j) {
            int c = c0 + 32 * j;
            outp[(size_t)(rowbase + r) * Ff + c] = (v[j] - mu) * inv * g2[c] + b2[c];
        }
    }
}

// ---------------------------------------------------------------- launch
extern "C" void kernel_launch(void* const* d_in, const int* in_sizes, int n_in,
                              void* d_out, int out_size, void* d_ws, size_t ws_size,
                              hipStream_t stream) {
    const float* a       = (const float*)d_in[0];
    const float* charges = (const float*)d_in[1];
    const int*   idx_j   = (const int*)  d_in[2];
    const float* d_ij    = (const float*)d_in[3];
    const void*  mask    =               d_in[4];
    const float* shifts  = (const float*)d_in[5];
    const float* Wq   = (const float*)d_in[6];  const float* bq   = (const float*)d_in[7];
    const float* Wk   = (const float*)d_in[8];  const float* bk   = (const float*)d_in[9];
    const float* Wv   = (const float*)d_in[10]; const float* bv   = (const float*)d_in[11];
    const float* Wrb  = (const float*)d_in[12]; const float* brb  = (const float*)d_in[13];
    const float* Wout = (const float*)d_in[14]; const float* bout = (const float*)d_in[15];
    const float* g1   = (const float*)d_in[16]; const float* b1   = (const float*)d_in[17];
    const float* g2   = (const float*)d_in[18]; const float* b2   = (const float*)d_in[19];
    const float* Wf1  = (const float*)d_in[20]; const float* bf1  = (const float*)d_in[21];
    const float* Wf2  = (const float*)d_in[22]; const float* bf2  = (const float*)d_in[23];
    float* outp = (float*)d_out;

    float* ws   = (float*)d_ws;
    int*   flag = (int*)d_ws;
    // ws layout: flag(1024 floats) | bf16 arena (3,899,392 ushorts = 7.8MB)
    unsigned short* arena = (unsigned short*)(ws + 1024);
    unsigned short* centerb = arena + OFF_CENTER;
    unsigned short* Wqkvb   = arena + OFF_WQKV;
    unsigned short* Woutb   = arena + OFF_WOUT;
    unsigned short* Wf1b    = arena + OFF_WF1;
    unsigned short* Wf2b    = arena + OFF_WF2;
    unsigned short* Ub      = arena + OFF_U;
    unsigned short* QKVB16  = arena + OFF_QKVB;

    hipMemsetAsync(flag, 0, sizeof(int), stream);
    prep<<<CONV_BLK + A2U_BLK + MSK_BLK, 256, 0, stream>>>(
        a, charges, Wq, Wk, Wv, Wout, Wf1, Wf2, (const unsigned char*)mask, flag, arena);

    qkv_gemm<<<128, 512, 0, stream>>>(centerb, Wqkvb, bq, bk, bv, QKVB16);

    attn_kernel<<<ROWS, 256, 0, stream>>>(QKVB16, idx_j, d_ij, mask, shifts, Wrb, brb, flag, Ub);

    tail_kernel<<<128, 512, 0, stream>>>(Ub, Woutb, Wf1b, Wf2b, a, bout, g1, b1, bf1, bf2, g2, b2, outp);
}